// Round 1
// baseline (438.929 us; speedup 1.0000x reference)
//
#include <hip/hip_runtime.h>

// FDTD 2-step update, float32.
// Fields: E (B,1024,1024), Hx (B,1022,1023), Hy (B,1023,1022), B=8.
// Output: concat along axis1 of (E_n,E_m), (Hx_n,Hx_m), (Hy_n,Hy_m), flattened
// in that order. Intermediates are written straight into their d_out slots.
//
// Stencil constants (DT/DX = DT/(Z*DY) = 0.5):
//   KF = 0.5*[-11/6, 3, -3/2, 1/3],  KB = -0.5*[1/3, -3/2, 3, -11/6]
// filt (3x4) = [[1,-1,1,0],[0,-1,1,0],[1,-1,1,0]] -> hardcoded add/sub chains.

#define KF0 (-11.0f / 12.0f)
#define KF1 (1.5f)
#define KF2 (-0.75f)
#define KF3 (1.0f / 6.0f)
#define KB0 (-1.0f / 6.0f)
#define KB1 (0.75f)
#define KB2 (-1.5f)
#define KB3 (11.0f / 12.0f)

// E_n[y,x] = E[y,x] + S1 - S2 over (1024,1024)
__global__ __launch_bounds__(256) void amper_k(
    const float* __restrict__ E, int sEb,
    const float* __restrict__ Hx, int sHxb,
    const float* __restrict__ Hy, int sHyb,
    float* __restrict__ Eo, int sEob)
{
    int x = blockIdx.x * 256 + threadIdx.x;   // 0..1023 exactly
    int y = blockIdx.y;                        // 0..1023
    int b = blockIdx.z;
    const float* e  = E  + (size_t)b * sEb;
    const float* hx = Hx + (size_t)b * sHxb;
    const float* hy = Hy + (size_t)b * sHyb;

    float v = e[y * 1024 + x];

    // Interior terms: 0.5*conv(Hy, f^T) and -0.5*conv(Hx, f), PAD1 region
    if ((y >= 2) & (y < 1022) & (x >= 2) & (x < 1022)) {
        const float* r0 = hy + (y - 2) * 1022 + (x - 2);
        const float* r1 = r0 + 1022;
        const float* r2 = r1 + 1022;
        // f^T rows: [1,0,1], [-1,-1,-1], [1,1,1], [0,0,0]
        v += 0.5f * ((r0[0] + r0[2])
                     - (r1[0] + r1[1] + r1[2])
                     + (r2[0] + r2[1] + r2[2]));
        const float* q0 = hx + (y - 2) * 1023 + (x - 2);
        const float* q1 = q0 + 1023;
        const float* q2 = q1 + 1023;
        // f rows: [1,-1,1,0], [0,-1,1,0], [1,-1,1,0]
        v -= 0.5f * ((q0[0] - q0[1] + q0[2])
                     + (-q1[1] + q1[2])
                     + (q2[0] - q2[1] + q2[2]));
    }
    // S1B: conv(Hy, KF^T) padded rows(0,4) cols(1,1): valid y<1020, 1<=x<1023
    bool cx = (x >= 1) & (x < 1023);
    if ((y < 1020) & cx) {
        const float* c = hy + y * 1022 + (x - 1);
        v += KF0 * c[0] + KF1 * c[1022] + KF2 * c[2044] + KF3 * c[3066];
    }
    // S1C: conv(Hy, KB^T) padded rows(4,0) cols(1,1): y>=4, 1<=x<1023
    if ((y >= 4) & cx) {
        const float* c = hy + (y - 4) * 1022 + (x - 1);
        v += KB0 * c[0] + KB1 * c[1022] + KB2 * c[2044] + KB3 * c[3066];
    }
    // S2B: conv(Hx, KF) padded rows(1,1) cols(0,4): 1<=y<1023, x<1020
    bool cy = (y >= 1) & (y < 1023);
    if (cy & (x < 1020)) {
        const float* r = hx + (y - 1) * 1023 + x;
        v -= KF0 * r[0] + KF1 * r[1] + KF2 * r[2] + KF3 * r[3];
    }
    // S2C: conv(Hx, KB) padded rows(1,1) cols(4,0): 1<=y<1023, x>=4
    if (cy & (x >= 4)) {
        const float* r = hx + (y - 1) * 1023 + (x - 4);
        v -= KB0 * r[0] + KB1 * r[1] + KB2 * r[2] + KB3 * r[3];
    }

    Eo[(size_t)b * sEob + y * 1024 + x] = v;
}

// Hx_n[y,x] = Hx - S3 over (1022,1023); Hy_n[y,x] = Hy + S4 over (1023,1022)
__global__ __launch_bounds__(256) void faraday_k(
    const float* __restrict__ E, int sEb,
    const float* __restrict__ Hx, int sHxb,
    const float* __restrict__ Hy, int sHyb,
    float* __restrict__ Hxo, int sHxob,
    float* __restrict__ Hyo, int sHyob)
{
    int x = blockIdx.x * 256 + threadIdx.x;   // 0..1023 (guarded)
    int y = blockIdx.y;                        // 0..1022
    int b = blockIdx.z;
    const float* e = E + (size_t)b * sEb;

    if ((x < 1023) & (y < 1022)) {
        float v = (Hx + (size_t)b * sHxb)[y * 1023 + x];
        // S3A: 0.5*conv(E,f) pad cols(1,1): 1<=x<1022
        if ((x >= 1) & (x < 1022)) {
            const float* r0 = e + y * 1024 + (x - 1);
            const float* r1 = r0 + 1024;
            const float* r2 = r1 + 1024;
            v -= 0.5f * ((r0[0] - r0[1] + r0[2])
                         + (-r1[1] + r1[2])
                         + (r2[0] - r2[1] + r2[2]));
        }
        // S3B: conv(E,KEF) pad cols(0,2), rows sliced 1:-1 -> row y+1, x<1021
        if (x < 1021) {
            const float* r = e + (y + 1) * 1024 + x;
            v -= KF0 * r[0] + KF1 * r[1] + KF2 * r[2] + KF3 * r[3];
        }
        // S3C: conv(E,KEB) pad cols(2,0), row y+1, x>=2
        if (x >= 2) {
            const float* r = e + (y + 1) * 1024 + (x - 2);
            v -= KB0 * r[0] + KB1 * r[1] + KB2 * r[2] + KB3 * r[3];
        }
        Hxo[(size_t)b * sHxob + y * 1023 + x] = v;
    }

    if (x < 1022) {  // y < 1023 guaranteed by grid
        float v = (Hy + (size_t)b * sHyb)[y * 1022 + x];
        // S4A: 0.5*conv(E,f^T) pad rows(1,1): 1<=y<1022
        if ((y >= 1) & (y < 1022)) {
            const float* r0 = e + (y - 1) * 1024 + x;
            const float* r1 = r0 + 1024;
            const float* r2 = r1 + 1024;
            v += 0.5f * ((r0[0] + r0[2])
                         - (r1[0] + r1[1] + r1[2])
                         + (r2[0] + r2[1] + r2[2]));
        }
        // S4B: conv(E,KEF^T) pad rows(0,2), cols sliced 1:-1 -> col x+1, y<1021
        if (y < 1021) {
            const float* c = e + y * 1024 + (x + 1);
            v += KF0 * c[0] + KF1 * c[1024] + KF2 * c[2048] + KF3 * c[3072];
        }
        // S4C: conv(E,KEB^T) pad rows(2,0), col x+1, y>=2
        if (y >= 2) {
            const float* c = e + (y - 2) * 1024 + (x + 1);
            v += KB0 * c[0] + KB1 * c[1024] + KB2 * c[2048] + KB3 * c[3072];
        }
        Hyo[(size_t)b * sHyob + y * 1022 + x] = v;
    }
}

extern "C" void kernel_launch(void* const* d_in, const int* in_sizes, int n_in,
                              void* d_out, int out_size, void* d_ws, size_t ws_size,
                              hipStream_t stream)
{
    const float* E  = (const float*)d_in[0];
    const float* Hx = (const float*)d_in[1];
    const float* Hy = (const float*)d_in[2];

    float* out = (float*)d_out;
    float* Eo  = out;                      // 8 * 2048 * 1024 = 16,777,216
    float* Hxo = out + 16777216;           // 8 * 2044 * 1023 = 16,728,096
    float* Hyo = Hxo + 16728096;           // 8 * 2046 * 1022 = 16,728,096

    const int sE = 1024 * 1024;            // input E batch stride
    const int sHx = 1022 * 1023;           // input Hx batch stride
    const int sHy = 1023 * 1022;           // input Hy batch stride
    const int sEo = 2 * 1024 * 1024;       // out E batch stride (concat axis1)
    const int sHo = 2 * 1045506;           // out Hx/Hy batch stride

    dim3 blk(256, 1, 1);
    dim3 gA(4, 1024, 8);
    dim3 gF(4, 1023, 8);

    // step 1: E_n = amper(E, Hx, Hy)
    amper_k<<<gA, blk, 0, stream>>>(E, sE, Hx, sHx, Hy, sHy, Eo, sEo);
    // step 2: Hx_n, Hy_n = faraday(E_n, Hx, Hy)
    faraday_k<<<gF, blk, 0, stream>>>(Eo, sEo, Hx, sHx, Hy, sHy,
                                      Hxo, sHo, Hyo, sHo);
    // step 3: E_m = amper(E_n, Hx_n, Hy_n)
    amper_k<<<gA, blk, 0, stream>>>(Eo, sEo, Hxo, sHo, Hyo, sHo,
                                    Eo + 1024 * 1024, sEo);
    // step 4: Hx_m, Hy_m = faraday(E_m, Hx_n, Hy_n)
    faraday_k<<<gF, blk, 0, stream>>>(Eo + 1024 * 1024, sEo, Hxo, sHo, Hyo, sHo,
                                      Hxo + 1045506, sHo, Hyo + 1045506, sHo);
}